// Round 12
// baseline (465.823 us; speedup 1.0000x reference)
//
#include <hip/hip_runtime.h>
#include <math.h>

#define NN 50000
#define EE 800000
#define HH 128
#define NTILES (EE/64)

typedef _Float16 f16;
typedef _Float16 f16x4 __attribute__((ext_vector_type(4)));
typedef _Float16 f16x8 __attribute__((ext_vector_type(8)));
typedef float f32x4 __attribute__((ext_vector_type(4)));

__device__ __forceinline__ float sigf(float x)  { return 1.0f/(1.0f+__expf(-x)); }
__device__ __forceinline__ float siluf(float x) { return x/(1.0f+__expf(-x)); }

// LDS-only barrier: orders LDS ops across the workgroup WITHOUT draining vmcnt.
// Global loads (prefetch) and fire-and-forget atomics stay in flight across it.
#define LBAR() do {                                          \
    __builtin_amdgcn_sched_barrier(0);                       \
    asm volatile("s_waitcnt lgkmcnt(0)" ::: "memory");       \
    __builtin_amdgcn_s_barrier();                            \
    __builtin_amdgcn_sched_barrier(0);                       \
  } while (0)

// ---------------- Kernel W: pre-swizzle weights into f16 fragment order ----------------
__global__ __launch_bounds__(256) void k_wswz(
    const float* __restrict__ Wi, const float* __restrict__ W1,
    const float* __restrict__ W2, const float* __restrict__ U1,
    const float* __restrict__ U2,
    f16* __restrict__ wis, f16* __restrict__ w1s, f16* __restrict__ w2s,
    f16* __restrict__ u1s, f16* __restrict__ u2s) {
  const int tid = blockIdx.x*256 + threadIdx.x;
  const float* src; f16* dst; int Ks, idx;
  if      (tid < 2048)  { src = Wi; dst = wis; Ks = 128; idx = tid;        }
  else if (tid < 4608)  { src = W1; dst = w1s; Ks = 136; idx = tid-2048;   }
  else if (tid < 6656)  { src = W2; dst = w2s; Ks = 128; idx = tid-4608;   }
  else if (tid < 10752) { src = U1; dst = u1s; Ks = 256; idx = tid-6656;   }
  else if (tid < 12800) { src = U2; dst = u2s; Ks = 128; idx = tid-10752;  }
  else return;
  const int l = idx & 63, c16 = (idx >> 6) & 7, ks = idx >> 9;
  const int col = c16*16 + (l & 15);
  const int kb  = ks*32 + (l >> 4)*8;
  f16x8 v;
  #pragma unroll
  for (int j = 0; j < 8; ++j) {
    const int k = kb + j;
    v[j] = (k < Ks) ? (f16)src[k*128 + col] : (f16)0.f;
  }
  *(f16x8*)&dst[(size_t)idx*8] = v;
}

// ---------------- Kernel A: h16 = f16(nf @ Wi + bi) ; hsum = rowsum ----------------
__global__ __launch_bounds__(256) void k_linin(
    const float* __restrict__ nf, const f16* __restrict__ wis,
    const float* __restrict__ bi, f16* __restrict__ h16, float* __restrict__ hsum) {
  __shared__ __align__(16) f16   Xl[64*136];
  __shared__ __align__(16) float Hl[64*132];
  const int t = threadIdx.x;
  const int w = t >> 6, l = t & 63;
  const int lr = l & 15, lg = l >> 4;

  f16x8 Wf[4][2];
  #pragma unroll
  for (int ks = 0; ks < 4; ++ks)
    #pragma unroll
    for (int nn = 0; nn < 2; ++nn)
      Wf[ks][nn] = *(const f16x8*)&wis[(size_t)(((ks*8) + (w*2+nn))*64 + l)*8];
  float biv[2];
  #pragma unroll
  for (int nn = 0; nn < 2; ++nn) biv[nn] = bi[w*32 + nn*16 + lr];

  for (int tile = blockIdx.x; tile < (NN+63)/64; tile += gridDim.x) {
    const int r0 = tile*64;
    __syncthreads();
    #pragma unroll
    for (int i = 0; i < 4; ++i) {
      const int ch = t + i*256;
      const int r = ch >> 4, co = (ch & 15)*8;
      const int gr = r0 + r;
      f16x8 v;
      if (gr < NN) {
        const float4 a = *(const float4*)&nf[(size_t)gr*128 + co];
        const float4 b = *(const float4*)&nf[(size_t)gr*128 + co + 4];
        v[0]=(f16)a.x; v[1]=(f16)a.y; v[2]=(f16)a.z; v[3]=(f16)a.w;
        v[4]=(f16)b.x; v[5]=(f16)b.y; v[6]=(f16)b.z; v[7]=(f16)b.w;
      } else {
        #pragma unroll
        for (int j = 0; j < 8; ++j) v[j] = (f16)0.f;
      }
      *(f16x8*)&Xl[r*136 + co] = v;
    }
    __syncthreads();
    f32x4 acc[4][2];
    #pragma unroll
    for (int mf = 0; mf < 4; ++mf)
      #pragma unroll
      for (int nn = 0; nn < 2; ++nn) acc[mf][nn] = (f32x4){0.f,0.f,0.f,0.f};
    #pragma unroll
    for (int ks = 0; ks < 4; ++ks)
      #pragma unroll
      for (int mf = 0; mf < 4; ++mf) {
        const f16x8 A = *(f16x8*)&Xl[(mf*16 + lr)*136 + ks*32 + lg*8];
        acc[mf][0] = __builtin_amdgcn_mfma_f32_16x16x32_f16(A, Wf[ks][0], acc[mf][0], 0, 0, 0);
        acc[mf][1] = __builtin_amdgcn_mfma_f32_16x16x32_f16(A, Wf[ks][1], acc[mf][1], 0, 0, 0);
      }
    #pragma unroll
    for (int mf = 0; mf < 4; ++mf)
      #pragma unroll
      for (int nn = 0; nn < 2; ++nn)
        #pragma unroll
        for (int j = 0; j < 4; ++j)
          Hl[(mf*16 + lg*4 + j)*132 + (w*32 + nn*16 + lr)] = acc[mf][nn][j] + biv[nn];
    __syncthreads();
    #pragma unroll
    for (int i = 0; i < 4; ++i) {
      const int ch = t + i*256;
      const int r = ch >> 4, co = (ch & 15)*8;
      const int gr = r0 + r;
      if (gr < NN) {
        f16x8 v;
        const float4 a = *(float4*)&Hl[r*132 + co];
        const float4 b = *(float4*)&Hl[r*132 + co + 4];
        v[0]=(f16)a.x; v[1]=(f16)a.y; v[2]=(f16)a.z; v[3]=(f16)a.w;
        v[4]=(f16)b.x; v[5]=(f16)b.y; v[6]=(f16)b.z; v[7]=(f16)b.w;
        *(f16x8*)&h16[(size_t)gr*256 + co] = v;
      }
    }
    {
      const int r = t >> 2, q = t & 3;
      const int gr = r0 + r;
      float s = 0.f;
      #pragma unroll
      for (int j = 0; j < 8; ++j) {
        const float4 v = *(float4*)&Hl[r*132 + q*32 + j*4];
        s += v.x + v.y + v.z + v.w;
      }
      s += __shfl_xor(s, 1, 4);
      s += __shfl_xor(s, 2, 4);
      if (q == 0 && gr < NN) hsum[gr] = s;
    }
  }
}

// ---------------- Sort kernels ----------------
__global__ void k_count(const int* __restrict__ ei, int* __restrict__ cnt) {
  const int e = blockIdx.x*256 + threadIdx.x;
  if (e < EE) atomicAdd(&cnt[ei[EE+e]], 1);
}

__global__ __launch_bounds__(1024) void k_scan(const int* __restrict__ cnt,
                                               int* __restrict__ cur) {
  __shared__ int part[1024];
  const int t = threadIdx.x;
  const int CH = 49;
  const int base = t*CH;
  int s = 0;
  for (int i = 0; i < CH; ++i) {
    const int idx = base+i;
    s += (idx < NN) ? cnt[idx] : 0;
  }
  part[t] = s;
  __syncthreads();
  for (int d = 1; d < 1024; d <<= 1) {
    int u = (t >= d) ? part[t-d] : 0;
    __syncthreads();
    part[t] += u;
    __syncthreads();
  }
  int run = part[t] - s;
  for (int i = 0; i < CH; ++i) {
    const int idx = base+i;
    if (idx < NN) { cur[idx] = run; run += cnt[idx]; }
  }
}

__global__ void k_scatter(const int* __restrict__ ei, int* __restrict__ cur,
                          int2* __restrict__ sE) {
  const int e = blockIdx.x*256 + threadIdx.x;
  if (e < EE) {
    const int d = ei[EE+e];
    const int p = atomicAdd(&cur[d], 1);
    sE[p] = make_int2(ei[e], d);
  }
}

// ---------------- Kernel B: r5-body edge MLP, LDS-only barriers, padded m1l ----------------
__global__ __launch_bounds__(256) void k_edge(
    const int2* __restrict__ sE,
    const float* __restrict__ pos, const f16* __restrict__ h16,
    const float* __restrict__ hsum,
    const f16* __restrict__ w1s, const float* __restrict__ b1,
    const f16* __restrict__ w2s,
    float* __restrict__ agg, float* __restrict__ gvsum) {
  __shared__ __align__(16) unsigned char smem[64*168*2 + 64*140*2];  // 39424 B
  __shared__ int   sdst[64];
  __shared__ float vred[64*3];
  __shared__ unsigned long long maskS;
  f16*   xl   = (f16*)smem;                    // [64][168] (row uses [0,160))
  f16*   m1l  = (f16*)(smem + 64*168*2);       // [64][140] (row uses [0,128)) — padded stride
  float* Mlds = (float*)smem;                  // [64][132] overlay (33792 <= 39424)

  const int t = threadIdx.x;
  const int w = t >> 6, l = t & 63;
  const int lr = l & 15, lg = l >> 4;
  const int le = t >> 2, q = t & 3;

  f16x8 W1f[5][2], W2f[4][2];
  #pragma unroll
  for (int ks = 0; ks < 5; ++ks)
    #pragma unroll
    for (int nn = 0; nn < 2; ++nn)
      W1f[ks][nn] = *(const f16x8*)&w1s[(size_t)(((ks*8) + (w*2+nn))*64 + l)*8];
  #pragma unroll
  for (int ks = 0; ks < 4; ++ks)
    #pragma unroll
    for (int nn = 0; nn < 2; ++nn)
      W2f[ks][nn] = *(const f16x8*)&w2s[(size_t)(((ks*8) + (w*2+nn))*64 + l)*8];
  float b1v[2];
  #pragma unroll
  for (int nn = 0; nn < 2; ++nn) b1v[nn] = b1[w*32 + nn*16 + lr];

  float vxa = 0.f, vya = 0.f, vza = 0.f;

  // ---- prefetch registers ----
  f16x8 pf[4];
  int   pd_s = 0;
  float psx = 0.f, psy = 0.f, psz = 0.f, pdx = 0.f, pdy = 0.f, pdz = 0.f, phs = 0.f;

  if (blockIdx.x < NTILES) {
    const int2 ed = sE[blockIdx.x*64 + le];
    const int s = ed.x;
    pd_s = ed.y;
    #pragma unroll
    for (int i = 0; i < 4; ++i)
      pf[i] = *(const f16x8*)&h16[(size_t)s*256 + q*32 + i*8];
    if (q == 0) {
      psx = pos[s*3+0]; psy = pos[s*3+1]; psz = pos[s*3+2];
      pdx = pos[pd_s*3+0]; pdy = pos[pd_s*3+1]; pdz = pos[pd_s*3+2];
      phs = hsum[s];
    }
  }

  for (int tile = blockIdx.x; tile < NTILES; tile += gridDim.x) {
    LBAR();   // previous reduce's LDS reads done (xl/Mlds/sdst/maskS free); atomics keep flying
    // ---- stage from prefetched regs (compiler waits vmcnt for pf here) ----
    #pragma unroll
    for (int i = 0; i < 4; ++i)
      *(f16x8*)&xl[le*168 + q*32 + i*8] = pf[i];
    if (q == 0) {
      sdst[le] = pd_s;
      const float rx = pdx - psx, ry = pdy - psy, rz = pdz - psz;
      const float dij = sqrtf(rx*rx+ry*ry+rz*rz);
      const float inv = 1.0f/(dij + 1e-8f);
      const float g = sigf(phs);
      vxa += g*rx*inv; vya += g*ry*inv; vza += g*rz*inv;
      #pragma unroll
      for (int qq = 0; qq < 8; ++qq) {
        const float dc = dij - (float)qq * (8.0f/7.0f);
        xl[le*168 + 128 + qq] = (f16)__expf(-0.5f*dc*dc);
      }
      f16x8 z;
      #pragma unroll
      for (int j = 0; j < 8; ++j) z[j] = (f16)0.f;
      *(f16x8*)&xl[le*168 + 136] = z;
      *(f16x8*)&xl[le*168 + 144] = z;
      *(f16x8*)&xl[le*168 + 152] = z;
    }
    // ---- issue prefetch for next tile (stays in flight across GEMMs+reduce) ----
    {
      int tn = tile + gridDim.x;
      if (tn >= NTILES) tn = tile;
      const int2 ed = sE[tn*64 + le];
      const int s = ed.x;
      pd_s = ed.y;
      #pragma unroll
      for (int i = 0; i < 4; ++i)
        pf[i] = *(const f16x8*)&h16[(size_t)s*256 + q*32 + i*8];
      if (q == 0) {
        psx = pos[s*3+0]; psy = pos[s*3+1]; psz = pos[s*3+2];
        pdx = pos[pd_s*3+0]; pdy = pos[pd_s*3+1]; pdz = pos[pd_s*3+2];
        phs = hsum[s];
      }
    }
    LBAR();   // staging visible; prefetch NOT drained
    // ---- dst-boundary mask (wave 0) ----
    if (t < 64) {
      const bool fl = (t == 63) || (sdst[t] != sdst[t+1]);
      const unsigned long long m = __ballot(fl);
      if (t == 0) maskS = m;
    }
    // ---- GEMM1: m1 = X @ W1, K=160 ----
    f32x4 acc[4][2];
    #pragma unroll
    for (int mf = 0; mf < 4; ++mf)
      #pragma unroll
      for (int nn = 0; nn < 2; ++nn)
        acc[mf][nn] = (f32x4){0.f,0.f,0.f,0.f};
    #pragma unroll
    for (int ks = 0; ks < 5; ++ks)
      #pragma unroll
      for (int mf = 0; mf < 4; ++mf) {
        const f16x8 A = *(f16x8*)&xl[(mf*16 + lr)*168 + ks*32 + lg*8];
        acc[mf][0] = __builtin_amdgcn_mfma_f32_16x16x32_f16(A, W1f[ks][0], acc[mf][0], 0, 0, 0);
        acc[mf][1] = __builtin_amdgcn_mfma_f32_16x16x32_f16(A, W1f[ks][1], acc[mf][1], 0, 0, 0);
      }
    #pragma unroll
    for (int mf = 0; mf < 4; ++mf)
      #pragma unroll
      for (int nn = 0; nn < 2; ++nn)
        #pragma unroll
        for (int j = 0; j < 4; ++j) {
          const float v = siluf(acc[mf][nn][j] + b1v[nn]);
          m1l[(mf*16 + lg*4 + j)*140 + (w*32 + nn*16 + lr)] = (f16)v;
        }
    LBAR();
    // ---- GEMM2: M = m1 @ W2, K=128 ----
    #pragma unroll
    for (int mf = 0; mf < 4; ++mf)
      #pragma unroll
      for (int nn = 0; nn < 2; ++nn)
        acc[mf][nn] = (f32x4){0.f,0.f,0.f,0.f};
    #pragma unroll
    for (int ks = 0; ks < 4; ++ks)
      #pragma unroll
      for (int mf = 0; mf < 4; ++mf) {
        const f16x8 A = *(f16x8*)&m1l[(mf*16 + lr)*140 + ks*32 + lg*8];
        acc[mf][0] = __builtin_amdgcn_mfma_f32_16x16x32_f16(A, W2f[ks][0], acc[mf][0], 0, 0, 0);
        acc[mf][1] = __builtin_amdgcn_mfma_f32_16x16x32_f16(A, W2f[ks][1], acc[mf][1], 0, 0, 0);
      }
    LBAR();   // all xl/m1l reads done; clobber with Mlds
    #pragma unroll
    for (int mf = 0; mf < 4; ++mf)
      #pragma unroll
      for (int nn = 0; nn < 2; ++nn)
        #pragma unroll
        for (int j = 0; j < 4; ++j)
          Mlds[(mf*16 + lg*4 + j)*132 + (w*32 + nn*16 + lr)] = acc[mf][nn][j];  // b2 folded into k_upd
    LBAR();
    // ---- segmented reduce: col-per-thread, coalesced fire-and-forget atomics ----
    {
      const int c = t & 127, hf = t >> 7;
      const unsigned long long mask = maskS;
      float run = 0.f;
      for (int r = hf*32; r < hf*32 + 32; ++r) {
        run += Mlds[r*132 + c];
        if (((mask >> r) & 1ull) || r == hf*32 + 31) {
          atomicAdd(&agg[(size_t)sdst[r]*128 + c], run);
          run = 0.f;
        }
      }
    }
  }
  __syncthreads();
  if (q == 0) { vred[le*3] = vxa; vred[le*3+1] = vya; vred[le*3+2] = vza; }
  __syncthreads();
  if (t < 3) {
    float s = 0.f;
    for (int i = 0; i < 64; ++i) s += vred[i*3 + t];
    atomicAdd(&gvsum[t], s);
  }
}

// ---------------- Kernel C: update MLP (f16 MFMA) + LayerNorm + g_P ----------------
__global__ __launch_bounds__(256) void k_upd(
    const f16* h16 /*aliases hn*/, const float* __restrict__ agg,
    const int* __restrict__ cnt, const float* __restrict__ b2,
    const f16* __restrict__ u1s, const float* __restrict__ u1,
    const f16* __restrict__ u2s, const float* __restrict__ u2,
    const float* __restrict__ lgm, const float* __restrict__ lbt,
    float* hn, float* __restrict__ gsum) {
  __shared__ __align__(16) f16   Xl[64*264];
  __shared__ __align__(16) f16   t1l[64*136];
  __shared__ __align__(16) float cred[4*128];
  float* HUl = (float*)Xl;

  const int t = threadIdx.x;
  const int w = t >> 6, l = t & 63;
  const int lr = l & 15, lg = l >> 4;

  f16x8 U1f[8][2], U2f[4][2];
  #pragma unroll
  for (int ks = 0; ks < 8; ++ks)
    #pragma unroll
    for (int nn = 0; nn < 2; ++nn)
      U1f[ks][nn] = *(const f16x8*)&u1s[(size_t)(((ks*8) + (w*2+nn))*64 + l)*8];
  #pragma unroll
  for (int ks = 0; ks < 4; ++ks)
    #pragma unroll
    for (int nn = 0; nn < 2; ++nn)
      U2f[ks][nn] = *(const f16x8*)&u2s[(size_t)(((ks*8) + (w*2+nn))*64 + l)*8];
  float u1v[2], u2v[2];
  #pragma unroll
  for (int nn = 0; nn < 2; ++nn) {
    u1v[nn] = u1[w*32 + nn*16 + lr];
    u2v[nn] = u2[w*32 + nn*16 + lr];
  }
  const int c0 = (t & 31)*4;
  const float4 gv4 = *(const float4*)&lgm[c0];
  const float4 bv4 = *(const float4*)&lbt[c0];
  float pc0=0, pc1=0, pc2=0, pc3=0;

  for (int tile = blockIdx.x; tile < (NN+63)/64; tile += gridDim.x) {
    const int r0 = tile*64;
    __syncthreads();
    #pragma unroll
    for (int i = 0; i < 4; ++i) {
      const int ch = t + i*256;
      const int r = ch >> 4, co = (ch & 15)*8;
      const int gr = r0 + r;
      f16x8 v;
      if (gr < NN) {
        v = *(const f16x8*)&h16[(size_t)gr*256 + co];
      } else {
        #pragma unroll
        for (int j = 0; j < 8; ++j) v[j] = (f16)0.f;
      }
      *(f16x8*)&Xl[r*264 + co] = v;
    }
    #pragma unroll
    for (int i = 0; i < 4; ++i) {
      const int ch = t + i*256;
      const int r = ch >> 4, co = (ch & 15)*8;
      const int gr = r0 + r;
      f16x8 v;
      if (gr < NN) {
        const float cb = (float)cnt[gr];
        const float4 a  = *(const float4*)&agg[(size_t)gr*128 + co];
        const float4 b  = *(const float4*)&agg[(size_t)gr*128 + co + 4];
        const float4 bA = *(const float4*)&b2[co];
        const float4 bB = *(const float4*)&b2[co + 4];
        v[0]=(f16)(a.x+cb*bA.x); v[1]=(f16)(a.y+cb*bA.y);
        v[2]=(f16)(a.z+cb*bA.z); v[3]=(f16)(a.w+cb*bA.w);
        v[4]=(f16)(b.x+cb*bB.x); v[5]=(f16)(b.y+cb*bB.y);
        v[6]=(f16)(b.z+cb*bB.z); v[7]=(f16)(b.w+cb*bB.w);
      } else {
        #pragma unroll
        for (int j = 0; j < 8; ++j) v[j] = (f16)0.f;
      }
      *(f16x8*)&Xl[r*264 + 128 + co] = v;
    }
    __syncthreads();
    f32x4 acc[4][2];
    #pragma unroll
    for (int mf = 0; mf < 4; ++mf)
      #pragma unroll
      for (int nn = 0; nn < 2; ++nn) acc[mf][nn] = (f32x4){0.f,0.f,0.f,0.f};
    #pragma unroll
    for (int ks = 0; ks < 8; ++ks)
      #pragma unroll
      for (int mf = 0; mf < 4; ++mf) {
        const f16x8 A = *(f16x8*)&Xl[(mf*16 + lr)*264 + ks*32 + lg*8];
        acc[mf][0] = __builtin_amdgcn_mfma_f32_16x16x32_f16(A, U1f[ks][0], acc[mf][0], 0, 0, 0);
        acc[mf][1] = __builtin_amdgcn_mfma_f32_16x16x32_f16(A, U1f[ks][1], acc[mf][1], 0, 0, 0);
      }
    #pragma unroll
    for (int mf = 0; mf < 4; ++mf)
      #pragma unroll
      for (int nn = 0; nn < 2; ++nn)
        #pragma unroll
        for (int j = 0; j < 4; ++j) {
          const float v = siluf(acc[mf][nn][j] + u1v[nn]);
          t1l[(mf*16 + lg*4 + j)*136 + (w*32 + nn*16 + lr)] = (f16)v;
        }
    __syncthreads();
    #pragma unroll
    for (int mf = 0; mf < 4; ++mf)
      #pragma unroll
      for (int nn = 0; nn < 2; ++nn) acc[mf][nn] = (f32x4){0.f,0.f,0.f,0.f};
    #pragma unroll
    for (int ks = 0; ks < 4; ++ks)
      #pragma unroll
      for (int mf = 0; mf < 4; ++mf) {
        const f16x8 A = *(f16x8*)&t1l[(mf*16 + lr)*136 + ks*32 + lg*8];
        acc[mf][0] = __builtin_amdgcn_mfma_f32_16x16x32_f16(A, U2f[ks][0], acc[mf][0], 0, 0, 0);
        acc[mf][1] = __builtin_amdgcn_mfma_f32_16x16x32_f16(A, U2f[ks][1], acc[mf][1], 0, 0, 0);
      }
    #pragma unroll
    for (int mf = 0; mf < 4; ++mf)
      #pragma unroll
      for (int nn = 0; nn < 2; ++nn)
        #pragma unroll
        for (int j = 0; j < 4; ++j)
          HUl[(mf*16 + lg*4 + j)*132 + (w*32 + nn*16 + lr)] = acc[mf][nn][j] + u2v[nn];
    __syncthreads();
    {
      const int rr0 = (t >> 5)*8;
      #pragma unroll
      for (int rr = 0; rr < 8; ++rr) {
        const int r = rr0 + rr;
        const int gr = r0 + r;
        const float4 v = *(float4*)&HUl[r*132 + c0];
        float s = v.x+v.y+v.z+v.w;
        float qq = v.x*v.x+v.y*v.y+v.z*v.z+v.w*v.w;
        #pragma unroll
        for (int m = 16; m > 0; m >>= 1) {
          s  += __shfl_xor(s,  m, 32);
          qq += __shfl_xor(qq, m, 32);
        }
        const float mu = s*(1.f/128.f);
        const float var = qq*(1.f/128.f) - mu*mu;
        const float rs = rsqrtf(var + 1e-5f);
        const float o0 = (v.x-mu)*rs*gv4.x + bv4.x;
        const float o1 = (v.y-mu)*rs*gv4.y + bv4.y;
        const float o2 = (v.z-mu)*rs*gv4.z + bv4.z;
        const float o3 = (v.w-mu)*rs*gv4.w + bv4.w;
        if (gr < NN) {
          *(float4*)&hn[(size_t)gr*128 + c0] = make_float4(o0,o1,o2,o3);
          pc0 += o0; pc1 += o1; pc2 += o2; pc3 += o3;
        }
      }
    }
  }
  pc0 += __shfl_xor(pc0, 32, 64);
  pc1 += __shfl_xor(pc1, 32, 64);
  pc2 += __shfl_xor(pc2, 32, 64);
  pc3 += __shfl_xor(pc3, 32, 64);
  __syncthreads();
  if ((t & 32) == 0) {
    const int ww = t >> 6;
    cred[ww*128 + c0+0] = pc0; cred[ww*128 + c0+1] = pc1;
    cred[ww*128 + c0+2] = pc2; cred[ww*128 + c0+3] = pc3;
  }
  __syncthreads();
  if (t < 128) {
    const float s = cred[t] + cred[128+t] + cred[256+t] + cred[384+t];
    atomicAdd(&gsum[t], s);
  }
}

// ---------------- Kernel D: finalize ----------------
__global__ void k_fin(const float* __restrict__ gsum, const float* __restrict__ gvsum,
                      float* __restrict__ gp, float* __restrict__ gvo) {
  const int t = threadIdx.x;
  if (t < 128) gp[t] = gsum[t] * (1.0f/NN);
  if (t == 0) {
    const float x = gvsum[0]*(1.0f/NN);
    const float y = gvsum[1]*(1.0f/NN);
    const float z = gvsum[2]*(1.0f/NN);
    const float n = sqrtf(x*x+y*y+z*z) + 1e-8f;
    gvo[0]=x/n; gvo[1]=y/n; gvo[2]=z/n;
  }
}

extern "C" void kernel_launch(void* const* d_in, const int* in_sizes, int n_in,
                              void* d_out, int out_size, void* d_ws, size_t ws_size,
                              hipStream_t stream) {
  const float* nf  = (const float*)d_in[0];
  const float* pos = (const float*)d_in[1];
  const int*   ei  = (const int*)d_in[2];
  const float* Wi  = (const float*)d_in[3];
  const float* bi  = (const float*)d_in[4];
  const float* W1  = (const float*)d_in[5];
  const float* b1  = (const float*)d_in[6];
  const float* W2  = (const float*)d_in[7];
  const float* b2  = (const float*)d_in[8];
  const float* U1  = (const float*)d_in[9];
  const float* u1  = (const float*)d_in[10];
  const float* U2  = (const float*)d_in[11];
  const float* u2  = (const float*)d_in[12];
  const float* lg  = (const float*)d_in[13];
  const float* lb  = (const float*)d_in[14];

  float* out = (float*)d_out;
  f16*   h16 = (f16*)d_out;                  // h16 row gr = first 256B of out row gr
  float* gp  = out + (size_t)NN*HH;
  float* gv  = gp + HH;

  // ---- workspace layout (4B units) ----
  int*   cnt   = (int*)d_ws;                       // [50176]
  float* gsum  = (float*)d_ws + 50176;             // [128]
  float* gvsum = (float*)d_ws + 50304;             // [4] (+pad)
  float* agg   = (float*)d_ws + 50432;             // [6,400,000]
  int*   cur   = (int*)d_ws + 6450432;             // [50176]
  int2*  sE    = (int2*)((int*)d_ws + 6500608);    // [800000] int2
  float* hsum  = (float*)d_ws + 8100608;           // [50000]
  f16*   wis   = (f16*)((float*)d_ws + 8150608);
  f16*   w1s   = (f16*)((float*)d_ws + 8158800);
  f16*   w2s   = (f16*)((float*)d_ws + 8169040);
  f16*   u1s   = (f16*)((float*)d_ws + 8177232);
  f16*   u2s   = (f16*)((float*)d_ws + 8193616);

  (void)hipMemsetAsync(d_ws, 0, (size_t)(50432 + 6400000) * sizeof(float), stream);

  k_wswz   <<<50,   256,  0, stream>>>(Wi, W1, W2, U1, U2, wis, w1s, w2s, u1s, u2s);
  k_linin  <<<782,  256,  0, stream>>>(nf, wis, bi, h16, hsum);
  k_count  <<<3125, 256,  0, stream>>>(ei, cnt);
  k_scan   <<<1,    1024, 0, stream>>>(cnt, cur);
  k_scatter<<<3125, 256,  0, stream>>>(ei, cur, sE);
  k_edge   <<<1024, 256,  0, stream>>>(sE, pos, h16, hsum,
                                       w1s, b1, w2s, agg, gvsum);
  k_upd    <<<782,  256,  0, stream>>>(h16, agg, cnt, b2, u1s, u1, u2s, u2,
                                       lg, lb, out, gsum);
  k_fin    <<<1,    128,  0, stream>>>(gsum, gvsum, gp, gv);
}

// Round 13
// 323.057 us; speedup vs baseline: 1.4419x; 1.4419x over previous
//
#include <hip/hip_runtime.h>
#include <math.h>

#define NN 50000
#define EE 800000
#define HH 128
#define NTILES (EE/64)

typedef _Float16 f16;
typedef _Float16 f16x4 __attribute__((ext_vector_type(4)));
typedef _Float16 f16x8 __attribute__((ext_vector_type(8)));
typedef float f32x4 __attribute__((ext_vector_type(4)));

__device__ __forceinline__ float sigf(float x)  { return 1.0f/(1.0f+__expf(-x)); }
__device__ __forceinline__ float siluf(float x) { return x/(1.0f+__expf(-x)); }

// ---------------- Kernel W: pre-swizzle weights into f16 fragment order ----------------
__global__ __launch_bounds__(256) void k_wswz(
    const float* __restrict__ Wi, const float* __restrict__ W1,
    const float* __restrict__ W2, const float* __restrict__ U1,
    const float* __restrict__ U2,
    f16* __restrict__ wis, f16* __restrict__ w1s, f16* __restrict__ w2s,
    f16* __restrict__ u1s, f16* __restrict__ u2s) {
  const int tid = blockIdx.x*256 + threadIdx.x;
  const float* src; f16* dst; int Ks, idx;
  if      (tid < 2048)  { src = Wi; dst = wis; Ks = 128; idx = tid;        }
  else if (tid < 4608)  { src = W1; dst = w1s; Ks = 136; idx = tid-2048;   }
  else if (tid < 6656)  { src = W2; dst = w2s; Ks = 128; idx = tid-4608;   }
  else if (tid < 10752) { src = U1; dst = u1s; Ks = 256; idx = tid-6656;   }
  else if (tid < 12800) { src = U2; dst = u2s; Ks = 128; idx = tid-10752;  }
  else return;
  const int l = idx & 63, c16 = (idx >> 6) & 7, ks = idx >> 9;
  const int col = c16*16 + (l & 15);
  const int kb  = ks*32 + (l >> 4)*8;
  f16x8 v;
  #pragma unroll
  for (int j = 0; j < 8; ++j) {
    const int k = kb + j;
    v[j] = (k < Ks) ? (f16)src[k*128 + col] : (f16)0.f;
  }
  *(f16x8*)&dst[(size_t)idx*8] = v;
}

// ---------------- Kernel A: h16 = f16(nf @ Wi + bi) ; hsum = rowsum ----------------
__global__ __launch_bounds__(256) void k_linin(
    const float* __restrict__ nf, const f16* __restrict__ wis,
    const float* __restrict__ bi, f16* __restrict__ h16, float* __restrict__ hsum) {
  __shared__ __align__(16) f16   Xl[64*136];
  __shared__ __align__(16) float Hl[64*132];
  const int t = threadIdx.x;
  const int w = t >> 6, l = t & 63;
  const int lr = l & 15, lg = l >> 4;

  f16x8 Wf[4][2];
  #pragma unroll
  for (int ks = 0; ks < 4; ++ks)
    #pragma unroll
    for (int nn = 0; nn < 2; ++nn)
      Wf[ks][nn] = *(const f16x8*)&wis[(size_t)(((ks*8) + (w*2+nn))*64 + l)*8];
  float biv[2];
  #pragma unroll
  for (int nn = 0; nn < 2; ++nn) biv[nn] = bi[w*32 + nn*16 + lr];

  for (int tile = blockIdx.x; tile < (NN+63)/64; tile += gridDim.x) {
    const int r0 = tile*64;
    __syncthreads();
    #pragma unroll
    for (int i = 0; i < 4; ++i) {
      const int ch = t + i*256;
      const int r = ch >> 4, co = (ch & 15)*8;
      const int gr = r0 + r;
      f16x8 v;
      if (gr < NN) {
        const float4 a = *(const float4*)&nf[(size_t)gr*128 + co];
        const float4 b = *(const float4*)&nf[(size_t)gr*128 + co + 4];
        v[0]=(f16)a.x; v[1]=(f16)a.y; v[2]=(f16)a.z; v[3]=(f16)a.w;
        v[4]=(f16)b.x; v[5]=(f16)b.y; v[6]=(f16)b.z; v[7]=(f16)b.w;
      } else {
        #pragma unroll
        for (int j = 0; j < 8; ++j) v[j] = (f16)0.f;
      }
      *(f16x8*)&Xl[r*136 + co] = v;
    }
    __syncthreads();
    f32x4 acc[4][2];
    #pragma unroll
    for (int mf = 0; mf < 4; ++mf)
      #pragma unroll
      for (int nn = 0; nn < 2; ++nn) acc[mf][nn] = (f32x4){0.f,0.f,0.f,0.f};
    #pragma unroll
    for (int ks = 0; ks < 4; ++ks)
      #pragma unroll
      for (int mf = 0; mf < 4; ++mf) {
        const f16x8 A = *(f16x8*)&Xl[(mf*16 + lr)*136 + ks*32 + lg*8];
        acc[mf][0] = __builtin_amdgcn_mfma_f32_16x16x32_f16(A, Wf[ks][0], acc[mf][0], 0, 0, 0);
        acc[mf][1] = __builtin_amdgcn_mfma_f32_16x16x32_f16(A, Wf[ks][1], acc[mf][1], 0, 0, 0);
      }
    #pragma unroll
    for (int mf = 0; mf < 4; ++mf)
      #pragma unroll
      for (int nn = 0; nn < 2; ++nn)
        #pragma unroll
        for (int j = 0; j < 4; ++j)
          Hl[(mf*16 + lg*4 + j)*132 + (w*32 + nn*16 + lr)] = acc[mf][nn][j] + biv[nn];
    __syncthreads();
    #pragma unroll
    for (int i = 0; i < 4; ++i) {
      const int ch = t + i*256;
      const int r = ch >> 4, co = (ch & 15)*8;
      const int gr = r0 + r;
      if (gr < NN) {
        f16x8 v;
        const float4 a = *(float4*)&Hl[r*132 + co];
        const float4 b = *(float4*)&Hl[r*132 + co + 4];
        v[0]=(f16)a.x; v[1]=(f16)a.y; v[2]=(f16)a.z; v[3]=(f16)a.w;
        v[4]=(f16)b.x; v[5]=(f16)b.y; v[6]=(f16)b.z; v[7]=(f16)b.w;
        *(f16x8*)&h16[(size_t)gr*256 + co] = v;
      }
    }
    {
      const int r = t >> 2, q = t & 3;
      const int gr = r0 + r;
      float s = 0.f;
      #pragma unroll
      for (int j = 0; j < 8; ++j) {
        const float4 v = *(float4*)&Hl[r*132 + q*32 + j*4];
        s += v.x + v.y + v.z + v.w;
      }
      s += __shfl_xor(s, 1, 4);
      s += __shfl_xor(s, 2, 4);
      if (q == 0 && gr < NN) hsum[gr] = s;
    }
  }
}

// ---------------- Sort kernels ----------------
__global__ void k_count(const int* __restrict__ ei, int* __restrict__ cnt) {
  const int e = blockIdx.x*256 + threadIdx.x;
  if (e < EE) atomicAdd(&cnt[ei[EE+e]], 1);
}

// parallel 3-phase exclusive scan of cnt[NN] -> cur[NN]
__global__ __launch_bounds__(256) void k_scanA(const int* __restrict__ cnt,
                                               int* __restrict__ cur,
                                               int* __restrict__ bsum) {
  __shared__ int sh[256];
  const int t = threadIdx.x, g = blockIdx.x*256 + t;
  const int v = (g < NN) ? cnt[g] : 0;
  sh[t] = v;
  __syncthreads();
  for (int d = 1; d < 256; d <<= 1) {
    const int u = (t >= d) ? sh[t-d] : 0;
    __syncthreads();
    sh[t] += u;
    __syncthreads();
  }
  if (g < NN) cur[g] = sh[t] - v;                 // exclusive within block
  if (t == 255) bsum[blockIdx.x] = sh[255];       // block total
}

__global__ __launch_bounds__(256) void k_scanB(int* __restrict__ bsum) {
  __shared__ int sh[256];
  const int t = threadIdx.x;
  const int v = (t < 196) ? bsum[t] : 0;
  sh[t] = v;
  __syncthreads();
  for (int d = 1; d < 256; d <<= 1) {
    const int u = (t >= d) ? sh[t-d] : 0;
    __syncthreads();
    sh[t] += u;
    __syncthreads();
  }
  if (t < 196) bsum[t] = sh[t] - v;               // exclusive block offsets
}

__global__ __launch_bounds__(256) void k_scanC(int* __restrict__ cur,
                                               const int* __restrict__ bsum) {
  const int g = blockIdx.x*256 + threadIdx.x;
  if (g < NN) cur[g] += bsum[blockIdx.x];
}

__global__ void k_scatter(const int* __restrict__ ei, int* __restrict__ cur,
                          int2* __restrict__ sE) {
  const int e = blockIdx.x*256 + threadIdx.x;
  if (e < EE) {
    const int d = ei[EE+e];
    const int p = atomicAdd(&cur[d], 1);
    sE[p] = make_int2(ei[e], d);
  }
}

// ---------------- Kernel B: r5-body edge MLP (non-transposed MFMA, occupancy-first) ----------------
__global__ __launch_bounds__(256) void k_edge(
    const int2* __restrict__ sE,
    const float* __restrict__ pos, const f16* __restrict__ h16,
    const float* __restrict__ hsum,
    const f16* __restrict__ w1s, const float* __restrict__ b1,
    const f16* __restrict__ w2s,
    float* __restrict__ agg, float* __restrict__ gvsum) {
  __shared__ __align__(16) unsigned char smem[64*168*2 + 64*136*2];  // 38912 B
  __shared__ int   sdst[64];
  __shared__ float vred[64*3];
  __shared__ unsigned long long maskS;
  f16*   xl   = (f16*)smem;                    // [64][168] (row uses [0,160))
  f16*   m1l  = (f16*)(smem + 64*168*2);       // [64][136] (row uses [0,128))
  float* Mlds = (float*)smem;                  // [64][132] overlay (33792 <= 38912)

  const int t = threadIdx.x;
  const int w = t >> 6, l = t & 63;
  const int lr = l & 15, lg = l >> 4;
  const int le = t >> 2, q = t & 3;

  f16x8 W1f[5][2], W2f[4][2];
  #pragma unroll
  for (int ks = 0; ks < 5; ++ks)
    #pragma unroll
    for (int nn = 0; nn < 2; ++nn)
      W1f[ks][nn] = *(const f16x8*)&w1s[(size_t)(((ks*8) + (w*2+nn))*64 + l)*8];
  #pragma unroll
  for (int ks = 0; ks < 4; ++ks)
    #pragma unroll
    for (int nn = 0; nn < 2; ++nn)
      W2f[ks][nn] = *(const f16x8*)&w2s[(size_t)(((ks*8) + (w*2+nn))*64 + l)*8];
  float b1v[2];
  #pragma unroll
  for (int nn = 0; nn < 2; ++nn) b1v[nn] = b1[w*32 + nn*16 + lr];

  float vxa = 0.f, vya = 0.f, vza = 0.f;

  // ---- prefetch registers ----
  f16x8 pf[4];
  int   pd_s = 0;
  float psx = 0.f, psy = 0.f, psz = 0.f, pdx = 0.f, pdy = 0.f, pdz = 0.f, phs = 0.f;

  if (blockIdx.x < NTILES) {
    const int2 ed = sE[blockIdx.x*64 + le];
    const int s = ed.x;
    pd_s = ed.y;
    #pragma unroll
    for (int i = 0; i < 4; ++i)
      pf[i] = *(const f16x8*)&h16[(size_t)s*256 + q*32 + i*8];
    if (q == 0) {
      psx = pos[s*3+0]; psy = pos[s*3+1]; psz = pos[s*3+2];
      pdx = pos[pd_s*3+0]; pdy = pos[pd_s*3+1]; pdz = pos[pd_s*3+2];
      phs = hsum[s];
    }
  }

  for (int tile = blockIdx.x; tile < NTILES; tile += gridDim.x) {
    __syncthreads();   // previous reduce done (xl/Mlds/sdst/maskS free)
    // ---- stage from prefetched regs ----
    #pragma unroll
    for (int i = 0; i < 4; ++i)
      *(f16x8*)&xl[le*168 + q*32 + i*8] = pf[i];
    if (q == 0) {
      sdst[le] = pd_s;
      const float rx = pdx - psx, ry = pdy - psy, rz = pdz - psz;
      const float dij = sqrtf(rx*rx+ry*ry+rz*rz);
      const float inv = 1.0f/(dij + 1e-8f);
      const float g = sigf(phs);
      vxa += g*rx*inv; vya += g*ry*inv; vza += g*rz*inv;
      #pragma unroll
      for (int qq = 0; qq < 8; ++qq) {
        const float dc = dij - (float)qq * (8.0f/7.0f);
        xl[le*168 + 128 + qq] = (f16)__expf(-0.5f*dc*dc);
      }
      f16x8 z;
      #pragma unroll
      for (int j = 0; j < 8; ++j) z[j] = (f16)0.f;
      *(f16x8*)&xl[le*168 + 136] = z;
      *(f16x8*)&xl[le*168 + 144] = z;
      *(f16x8*)&xl[le*168 + 152] = z;
    }
    // ---- issue prefetch for next tile ----
    {
      int tn = tile + gridDim.x;
      if (tn >= NTILES) tn = tile;
      const int2 ed = sE[tn*64 + le];
      const int s = ed.x;
      pd_s = ed.y;
      #pragma unroll
      for (int i = 0; i < 4; ++i)
        pf[i] = *(const f16x8*)&h16[(size_t)s*256 + q*32 + i*8];
      if (q == 0) {
        psx = pos[s*3+0]; psy = pos[s*3+1]; psz = pos[s*3+2];
        pdx = pos[pd_s*3+0]; pdy = pos[pd_s*3+1]; pdz = pos[pd_s*3+2];
        phs = hsum[s];
      }
    }
    __syncthreads();
    // ---- dst-boundary mask (wave 0) ----
    if (t < 64) {
      const bool fl = (t == 63) || (sdst[t] != sdst[t+1]);
      const unsigned long long m = __ballot(fl);
      if (t == 0) maskS = m;
    }
    // ---- GEMM1: m1 = X @ W1, K=160 ----
    f32x4 acc[4][2];
    #pragma unroll
    for (int mf = 0; mf < 4; ++mf)
      #pragma unroll
      for (int nn = 0; nn < 2; ++nn)
        acc[mf][nn] = (f32x4){0.f,0.f,0.f,0.f};
    #pragma unroll
    for (int ks = 0; ks < 5; ++ks)
      #pragma unroll
      for (int mf = 0; mf < 4; ++mf) {
        const f16x8 A = *(f16x8*)&xl[(mf*16 + lr)*168 + ks*32 + lg*8];
        acc[mf][0] = __builtin_amdgcn_mfma_f32_16x16x32_f16(A, W1f[ks][0], acc[mf][0], 0, 0, 0);
        acc[mf][1] = __builtin_amdgcn_mfma_f32_16x16x32_f16(A, W1f[ks][1], acc[mf][1], 0, 0, 0);
      }
    #pragma unroll
    for (int mf = 0; mf < 4; ++mf)
      #pragma unroll
      for (int nn = 0; nn < 2; ++nn)
        #pragma unroll
        for (int j = 0; j < 4; ++j) {
          const float v = siluf(acc[mf][nn][j] + b1v[nn]);
          m1l[(mf*16 + lg*4 + j)*136 + (w*32 + nn*16 + lr)] = (f16)v;
        }
    __syncthreads();
    // ---- GEMM2: M = m1 @ W2, K=128 ----
    #pragma unroll
    for (int mf = 0; mf < 4; ++mf)
      #pragma unroll
      for (int nn = 0; nn < 2; ++nn)
        acc[mf][nn] = (f32x4){0.f,0.f,0.f,0.f};
    #pragma unroll
    for (int ks = 0; ks < 4; ++ks)
      #pragma unroll
      for (int mf = 0; mf < 4; ++mf) {
        const f16x8 A = *(f16x8*)&m1l[(mf*16 + lr)*136 + ks*32 + lg*8];
        acc[mf][0] = __builtin_amdgcn_mfma_f32_16x16x32_f16(A, W2f[ks][0], acc[mf][0], 0, 0, 0);
        acc[mf][1] = __builtin_amdgcn_mfma_f32_16x16x32_f16(A, W2f[ks][1], acc[mf][1], 0, 0, 0);
      }
    __syncthreads();   // all xl/m1l reads done; clobber with Mlds
    #pragma unroll
    for (int mf = 0; mf < 4; ++mf)
      #pragma unroll
      for (int nn = 0; nn < 2; ++nn)
        #pragma unroll
        for (int j = 0; j < 4; ++j)
          Mlds[(mf*16 + lg*4 + j)*132 + (w*32 + nn*16 + lr)] = acc[mf][nn][j];  // b2 folded into k_upd
    __syncthreads();
    // ---- segmented reduce: col-per-thread, coalesced atomic flushes ----
    {
      const int c = t & 127, hf = t >> 7;
      const unsigned long long mask = maskS;
      float run = 0.f;
      for (int r = hf*32; r < hf*32 + 32; ++r) {
        run += Mlds[r*132 + c];
        if (((mask >> r) & 1ull) || r == hf*32 + 31) {
          atomicAdd(&agg[(size_t)sdst[r]*128 + c], run);
          run = 0.f;
        }
      }
    }
  }
  __syncthreads();
  if (q == 0) { vred[le*3] = vxa; vred[le*3+1] = vya; vred[le*3+2] = vza; }
  __syncthreads();
  if (t < 3) {
    float s = 0.f;
    for (int i = 0; i < 64; ++i) s += vred[i*3 + t];
    atomicAdd(&gvsum[t], s);
  }
}

// ---------------- Kernel C: update MLP (f16 MFMA) + LayerNorm + g_P ----------------
__global__ __launch_bounds__(256) void k_upd(
    const f16* h16 /*aliases hn*/, const float* __restrict__ agg,
    const int* __restrict__ cnt, const float* __restrict__ b2,
    const f16* __restrict__ u1s, const float* __restrict__ u1,
    const f16* __restrict__ u2s, const float* __restrict__ u2,
    const float* __restrict__ lgm, const float* __restrict__ lbt,
    float* hn, float* __restrict__ gsum) {
  __shared__ __align__(16) f16   Xl[64*264];
  __shared__ __align__(16) f16   t1l[64*136];
  __shared__ __align__(16) float cred[4*128];
  float* HUl = (float*)Xl;

  const int t = threadIdx.x;
  const int w = t >> 6, l = t & 63;
  const int lr = l & 15, lg = l >> 4;

  f16x8 U1f[8][2], U2f[4][2];
  #pragma unroll
  for (int ks = 0; ks < 8; ++ks)
    #pragma unroll
    for (int nn = 0; nn < 2; ++nn)
      U1f[ks][nn] = *(const f16x8*)&u1s[(size_t)(((ks*8) + (w*2+nn))*64 + l)*8];
  #pragma unroll
  for (int ks = 0; ks < 4; ++ks)
    #pragma unroll
    for (int nn = 0; nn < 2; ++nn)
      U2f[ks][nn] = *(const f16x8*)&u2s[(size_t)(((ks*8) + (w*2+nn))*64 + l)*8];
  float u1v[2], u2v[2];
  #pragma unroll
  for (int nn = 0; nn < 2; ++nn) {
    u1v[nn] = u1[w*32 + nn*16 + lr];
    u2v[nn] = u2[w*32 + nn*16 + lr];
  }
  const int c0 = (t & 31)*4;
  const float4 gv4 = *(const float4*)&lgm[c0];
  const float4 bv4 = *(const float4*)&lbt[c0];
  float pc0=0, pc1=0, pc2=0, pc3=0;

  for (int tile = blockIdx.x; tile < (NN+63)/64; tile += gridDim.x) {
    const int r0 = tile*64;
    __syncthreads();
    #pragma unroll
    for (int i = 0; i < 4; ++i) {
      const int ch = t + i*256;
      const int r = ch >> 4, co = (ch & 15)*8;
      const int gr = r0 + r;
      f16x8 v;
      if (gr < NN) {
        v = *(const f16x8*)&h16[(size_t)gr*256 + co];
      } else {
        #pragma unroll
        for (int j = 0; j < 8; ++j) v[j] = (f16)0.f;
      }
      *(f16x8*)&Xl[r*264 + co] = v;
    }
    #pragma unroll
    for (int i = 0; i < 4; ++i) {
      const int ch = t + i*256;
      const int r = ch >> 4, co = (ch & 15)*8;
      const int gr = r0 + r;
      f16x8 v;
      if (gr < NN) {
        const float cb = (float)cnt[gr];
        const float4 a  = *(const float4*)&agg[(size_t)gr*128 + co];
        const float4 b  = *(const float4*)&agg[(size_t)gr*128 + co + 4];
        const float4 bA = *(const float4*)&b2[co];
        const float4 bB = *(const float4*)&b2[co + 4];
        v[0]=(f16)(a.x+cb*bA.x); v[1]=(f16)(a.y+cb*bA.y);
        v[2]=(f16)(a.z+cb*bA.z); v[3]=(f16)(a.w+cb*bA.w);
        v[4]=(f16)(b.x+cb*bB.x); v[5]=(f16)(b.y+cb*bB.y);
        v[6]=(f16)(b.z+cb*bB.z); v[7]=(f16)(b.w+cb*bB.w);
      } else {
        #pragma unroll
        for (int j = 0; j < 8; ++j) v[j] = (f16)0.f;
      }
      *(f16x8*)&Xl[r*264 + 128 + co] = v;
    }
    __syncthreads();
    f32x4 acc[4][2];
    #pragma unroll
    for (int mf = 0; mf < 4; ++mf)
      #pragma unroll
      for (int nn = 0; nn < 2; ++nn) acc[mf][nn] = (f32x4){0.f,0.f,0.f,0.f};
    #pragma unroll
    for (int ks = 0; ks < 8; ++ks)
      #pragma unroll
      for (int mf = 0; mf < 4; ++mf) {
        const f16x8 A = *(f16x8*)&Xl[(mf*16 + lr)*264 + ks*32 + lg*8];
        acc[mf][0] = __builtin_amdgcn_mfma_f32_16x16x32_f16(A, U1f[ks][0], acc[mf][0], 0, 0, 0);
        acc[mf][1] = __builtin_amdgcn_mfma_f32_16x16x32_f16(A, U1f[ks][1], acc[mf][1], 0, 0, 0);
      }
    #pragma unroll
    for (int mf = 0; mf < 4; ++mf)
      #pragma unroll
      for (int nn = 0; nn < 2; ++nn)
        #pragma unroll
        for (int j = 0; j < 4; ++j) {
          const float v = siluf(acc[mf][nn][j] + u1v[nn]);
          t1l[(mf*16 + lg*4 + j)*136 + (w*32 + nn*16 + lr)] = (f16)v;
        }
    __syncthreads();
    #pragma unroll
    for (int mf = 0; mf < 4; ++mf)
      #pragma unroll
      for (int nn = 0; nn < 2; ++nn) acc[mf][nn] = (f32x4){0.f,0.f,0.f,0.f};
    #pragma unroll
    for (int ks = 0; ks < 4; ++ks)
      #pragma unroll
      for (int mf = 0; mf < 4; ++mf) {
        const f16x8 A = *(f16x8*)&t1l[(mf*16 + lr)*136 + ks*32 + lg*8];
        acc[mf][0] = __builtin_amdgcn_mfma_f32_16x16x32_f16(A, U2f[ks][0], acc[mf][0], 0, 0, 0);
        acc[mf][1] = __builtin_amdgcn_mfma_f32_16x16x32_f16(A, U2f[ks][1], acc[mf][1], 0, 0, 0);
      }
    #pragma unroll
    for (int mf = 0; mf < 4; ++mf)
      #pragma unroll
      for (int nn = 0; nn < 2; ++nn)
        #pragma unroll
        for (int j = 0; j < 4; ++j)
          HUl[(mf*16 + lg*4 + j)*132 + (w*32 + nn*16 + lr)] = acc[mf][nn][j] + u2v[nn];
    __syncthreads();
    {
      const int rr0 = (t >> 5)*8;
      #pragma unroll
      for (int rr = 0; rr < 8; ++rr) {
        const int r = rr0 + rr;
        const int gr = r0 + r;
        const float4 v = *(float4*)&HUl[r*132 + c0];
        float s = v.x+v.y+v.z+v.w;
        float qq = v.x*v.x+v.y*v.y+v.z*v.z+v.w*v.w;
        #pragma unroll
        for (int m = 16; m > 0; m >>= 1) {
          s  += __shfl_xor(s,  m, 32);
          qq += __shfl_xor(qq, m, 32);
        }
        const float mu = s*(1.f/128.f);
        const float var = qq*(1.f/128.f) - mu*mu;
        const float rs = rsqrtf(var + 1e-5f);
        const float o0 = (v.x-mu)*rs*gv4.x + bv4.x;
        const float o1 = (v.y-mu)*rs*gv4.y + bv4.y;
        const float o2 = (v.z-mu)*rs*gv4.z + bv4.z;
        const float o3 = (v.w-mu)*rs*gv4.w + bv4.w;
        if (gr < NN) {
          *(float4*)&hn[(size_t)gr*128 + c0] = make_float4(o0,o1,o2,o3);
          pc0 += o0; pc1 += o1; pc2 += o2; pc3 += o3;
        }
      }
    }
  }
  pc0 += __shfl_xor(pc0, 32, 64);
  pc1 += __shfl_xor(pc1, 32, 64);
  pc2 += __shfl_xor(pc2, 32, 64);
  pc3 += __shfl_xor(pc3, 32, 64);
  __syncthreads();
  if ((t & 32) == 0) {
    const int ww = t >> 6;
    cred[ww*128 + c0+0] = pc0; cred[ww*128 + c0+1] = pc1;
    cred[ww*128 + c0+2] = pc2; cred[ww*128 + c0+3] = pc3;
  }
  __syncthreads();
  if (t < 128) {
    const float s = cred[t] + cred[128+t] + cred[256+t] + cred[384+t];
    atomicAdd(&gsum[t], s);
  }
}

// ---------------- Kernel D: finalize ----------------
__global__ void k_fin(const float* __restrict__ gsum, const float* __restrict__ gvsum,
                      float* __restrict__ gp, float* __restrict__ gvo) {
  const int t = threadIdx.x;
  if (t < 128) gp[t] = gsum[t] * (1.0f/NN);
  if (t == 0) {
    const float x = gvsum[0]*(1.0f/NN);
    const float y = gvsum[1]*(1.0f/NN);
    const float z = gvsum[2]*(1.0f/NN);
    const float n = sqrtf(x*x+y*y+z*z) + 1e-8f;
    gvo[0]=x/n; gvo[1]=y/n; gvo[2]=z/n;
  }
}

extern "C" void kernel_launch(void* const* d_in, const int* in_sizes, int n_in,
                              void* d_out, int out_size, void* d_ws, size_t ws_size,
                              hipStream_t stream) {
  const float* nf  = (const float*)d_in[0];
  const float* pos = (const float*)d_in[1];
  const int*   ei  = (const int*)d_in[2];
  const float* Wi  = (const float*)d_in[3];
  const float* bi  = (const float*)d_in[4];
  const float* W1  = (const float*)d_in[5];
  const float* b1  = (const float*)d_in[6];
  const float* W2  = (const float*)d_in[7];
  const float* b2  = (const float*)d_in[8];
  const float* U1  = (const float*)d_in[9];
  const float* u1  = (const float*)d_in[10];
  const float* U2  = (const float*)d_in[11];
  const float* u2  = (const float*)d_in[12];
  const float* lg  = (const float*)d_in[13];
  const float* lb  = (const float*)d_in[14];

  float* out = (float*)d_out;
  f16*   h16 = (f16*)d_out;                  // h16 row gr = first 256B of out row gr
  float* gp  = out + (size_t)NN*HH;
  float* gv  = gp + HH;

  // ---- workspace layout (4B units) ----
  int*   cnt   = (int*)d_ws;                       // [50176]
  float* gsum  = (float*)d_ws + 50176;             // [128]
  float* gvsum = (float*)d_ws + 50304;             // [4] (+pad)
  float* agg   = (float*)d_ws + 50432;             // [6,400,000]
  int*   cur   = (int*)d_ws + 6450432;             // [50176]
  int2*  sE    = (int2*)((int*)d_ws + 6500608);    // [800000] int2
  float* hsum  = (float*)d_ws + 8100608;           // [50000]
  f16*   wis   = (f16*)((float*)d_ws + 8150608);
  f16*   w1s   = (f16*)((float*)d_ws + 8158800);
  f16*   w2s   = (f16*)((float*)d_ws + 8169040);
  f16*   u1s   = (f16*)((float*)d_ws + 8177232);
  f16*   u2s   = (f16*)((float*)d_ws + 8193616);
  int*   bsum  = (int*)d_ws + 8201808;             // [256]

  (void)hipMemsetAsync(d_ws, 0, (size_t)(50432 + 6400000) * sizeof(float), stream);

  k_wswz   <<<50,   256,  0, stream>>>(Wi, W1, W2, U1, U2, wis, w1s, w2s, u1s, u2s);
  k_linin  <<<782,  256,  0, stream>>>(nf, wis, bi, h16, hsum);
  k_count  <<<3125, 256,  0, stream>>>(ei, cnt);
  k_scanA  <<<196,  256,  0, stream>>>(cnt, cur, bsum);
  k_scanB  <<<1,    256,  0, stream>>>(bsum);
  k_scanC  <<<196,  256,  0, stream>>>(cur, bsum);
  k_scatter<<<3125, 256,  0, stream>>>(ei, cur, sE);
  k_edge   <<<1024, 256,  0, stream>>>(sE, pos, h16, hsum,
                                       w1s, b1, w2s, agg, gvsum);
  k_upd    <<<782,  256,  0, stream>>>(h16, agg, cnt, b2, u1s, u1, u2s, u2,
                                       lg, lb, out, gsum);
  k_fin    <<<1,    128,  0, stream>>>(gsum, gvsum, gp, gv);
}